// Round 1
// baseline (752.789 us; speedup 1.0000x reference)
//
#include <hip/hip_runtime.h>
#include <cstddef>

constexpr int Bn = 4096;
constexpr int Sn = 200;
constexpr int Hn = 512;
constexpr int On = 64;
constexpr int K1 = 576; // Hn + On

constexpr size_t HNEW_OFF = (size_t)Bn * On;                    // h_new region
constexpr size_t AW_OFF   = (size_t)Bn * On + (size_t)Bn * Hn;  // attn_weights region

__device__ __forceinline__ float sigmoidf_(float v) { return 1.f / (1.f + __expf(-v)); }

// ---------------------------------------------------------------------------
// Kernel A: scores = softmax([last_input | h0] @ attn_W^T + attn_b)
// 8 b-rows per block; thread s = tid (s<200); cat1 row staged in LDS.
// ---------------------------------------------------------------------------
__global__ __launch_bounds__(256) void attn_scores_kernel(
    const float* __restrict__ last_input, const float* __restrict__ hidden,
    const float* __restrict__ attn_W, const float* __restrict__ attn_b,
    float* __restrict__ dout)
{
    __shared__ float cat1[8 * K1];
    __shared__ float red[4];
    const int tid = threadIdx.x;
    const int b0 = blockIdx.x * 8;

    for (int idx = tid; idx < 8 * K1; idx += 256) {
        int r = idx / K1, k = idx - r * K1;
        float v = (k < On) ? last_input[(size_t)(b0 + r) * On + k]
                           : hidden[(size_t)(b0 + r) * Hn + (k - On)];
        cat1[idx] = v;
    }
    __syncthreads();

    const int s = tid;
    float acc[8];
#pragma unroll
    for (int r = 0; r < 8; ++r) acc[r] = 0.f;

    if (s < Sn) {
        const float4* wp = (const float4*)(attn_W + (size_t)s * K1);
#pragma unroll 4
        for (int k4 = 0; k4 < K1 / 4; ++k4) {
            float4 w4 = wp[k4];
#pragma unroll
            for (int r = 0; r < 8; ++r) {
                float4 a4 = *(const float4*)&cat1[r * K1 + k4 * 4];
                acc[r] += w4.x * a4.x + w4.y * a4.y + w4.z * a4.z + w4.w * a4.w;
            }
        }
        float bb = attn_b[s];
#pragma unroll
        for (int r = 0; r < 8; ++r) acc[r] += bb;
    }

    const int lane = tid & 63, wid = tid >> 6;
    for (int r = 0; r < 8; ++r) {
        float v = (s < Sn) ? acc[r] : -3.0e38f;
#pragma unroll
        for (int o = 32; o > 0; o >>= 1) v = fmaxf(v, __shfl_xor(v, o, 64));
        if (lane == 0) red[wid] = v;
        __syncthreads();
        float m = fmaxf(fmaxf(red[0], red[1]), fmaxf(red[2], red[3]));
        __syncthreads();
        float e = (s < Sn) ? __expf(acc[r] - m) : 0.f;
        float t = e;
#pragma unroll
        for (int o = 32; o > 0; o >>= 1) t += __shfl_xor(t, o, 64);
        if (lane == 0) red[wid] = t;
        __syncthreads();
        float sum = red[0] + red[1] + red[2] + red[3];
        __syncthreads();
        if (s < Sn) dout[AW_OFF + (size_t)(b0 + r) * Sn + s] = e / sum;
    }
}

// ---------------------------------------------------------------------------
// Kernel B: attn_applied[b,h] = sum_s w[b,s] * enc[s,b,h]   (1.68 GB stream)
// 4 b-rows per block; each s-iteration reads one contiguous 8 KB chunk.
// ---------------------------------------------------------------------------
__global__ __launch_bounds__(256) void attn_apply_kernel(
    const float* __restrict__ enc, const float* __restrict__ aw,
    float* __restrict__ attnA)
{
    __shared__ float wl[4 * Sn];
    const int tid = threadIdx.x;
    const int b0 = blockIdx.x * 4;

    for (int idx = tid; idx < 4 * Sn; idx += 256)
        wl[idx] = aw[(size_t)b0 * Sn + idx];  // rows contiguous: [4][200]
    __syncthreads();

    const int bi0 = tid >> 7;  // 0 or 1
    const int bi1 = bi0 + 2;
    float4 acc0 = {0, 0, 0, 0}, acc1 = {0, 0, 0, 0};

#pragma unroll 4
    for (int s = 0; s < Sn; ++s) {
        const float4* p = (const float4*)(enc + ((size_t)s * Bn + b0) * Hn);
        float4 v0 = p[tid];
        float4 v1 = p[tid + 256];
        float w0 = wl[bi0 * Sn + s];
        float w1 = wl[bi1 * Sn + s];
        acc0.x += w0 * v0.x; acc0.y += w0 * v0.y; acc0.z += w0 * v0.z; acc0.w += w0 * v0.w;
        acc1.x += w1 * v1.x; acc1.y += w1 * v1.y; acc1.z += w1 * v1.z; acc1.w += w1 * v1.w;
    }
    float4* outp = (float4*)(attnA + (size_t)b0 * Hn);
    outp[tid] = acc0;
    outp[tid + 256] = acc1;
}

// ---------------------------------------------------------------------------
// Kernel C: x = relu([last_input | attn_applied] @ comb_W^T + comb_b)
// M=4096 N=512 K=576. BM=128 BN=64 BK=32, 8x4 thread tile.
// ---------------------------------------------------------------------------
__global__ __launch_bounds__(256) void comb_kernel(
    const float* __restrict__ last_input, const float* __restrict__ attnA,
    const float* __restrict__ comb_W, const float* __restrict__ comb_b,
    float* __restrict__ x)
{
    __shared__ float As[32 * 128];  // [k][m]
    __shared__ float Bs[32 * 64];   // [k][n]
    const int tid = threadIdx.x;
    const int b0 = blockIdx.x * 128;
    const int n0 = blockIdx.y * 64;
    const int tm = (tid & 15) * 8;
    const int tn = (tid >> 4) * 4;

    float acc[8][4] = {};

    for (int kc = 0; kc < K1; kc += 32) {
        __syncthreads();
#pragma unroll
        for (int i = 0; i < 4; ++i) {
            int f = tid + i * 256;
            int row = f >> 3, kk4 = (f & 7) * 4;
            int k = kc + kk4;
            const float* src = (k < On)
                ? (last_input + (size_t)(b0 + row) * On + k)
                : (attnA + (size_t)(b0 + row) * Hn + (k - On));
            float4 v = *(const float4*)src;
            As[(kk4 + 0) * 128 + row] = v.x;
            As[(kk4 + 1) * 128 + row] = v.y;
            As[(kk4 + 2) * 128 + row] = v.z;
            As[(kk4 + 3) * 128 + row] = v.w;
        }
#pragma unroll
        for (int i = 0; i < 2; ++i) {
            int f = tid + i * 256;
            int row = f >> 3, kk4 = (f & 7) * 4;
            float4 v = *(const float4*)(comb_W + (size_t)(n0 + row) * K1 + kc + kk4);
            Bs[(kk4 + 0) * 64 + row] = v.x;
            Bs[(kk4 + 1) * 64 + row] = v.y;
            Bs[(kk4 + 2) * 64 + row] = v.z;
            Bs[(kk4 + 3) * 64 + row] = v.w;
        }
        __syncthreads();
#pragma unroll
        for (int kk = 0; kk < 32; ++kk) {
            float4 A0 = *(const float4*)&As[kk * 128 + tm];
            float4 A1 = *(const float4*)&As[kk * 128 + tm + 4];
            float4 Bv = *(const float4*)&Bs[kk * 64 + tn];
            float a[8] = {A0.x, A0.y, A0.z, A0.w, A1.x, A1.y, A1.z, A1.w};
            float bb[4] = {Bv.x, Bv.y, Bv.z, Bv.w};
#pragma unroll
            for (int r = 0; r < 8; ++r)
#pragma unroll
                for (int j = 0; j < 4; ++j) acc[r][j] += a[r] * bb[j];
        }
    }

    float4 bj = *(const float4*)&comb_b[n0 + tn];
    float bja[4] = {bj.x, bj.y, bj.z, bj.w};
#pragma unroll
    for (int r = 0; r < 8; ++r) {
        float4 c;
        c.x = fmaxf(acc[r][0] + bja[0], 0.f);
        c.y = fmaxf(acc[r][1] + bja[1], 0.f);
        c.z = fmaxf(acc[r][2] + bja[2], 0.f);
        c.w = fmaxf(acc[r][3] + bja[3], 0.f);
        *(float4*)&x[(size_t)(b0 + tm + r) * Hn + n0 + tn] = c;
    }
}

// ---------------------------------------------------------------------------
// Kernel D: fused GRU gates. Per block computes 6 GEMM tiles:
// gi_{r,z,n} = x @ w_ih^T,  gh_{r,z,n} = h0 @ w_hh^T, then elementwise GRU.
// M=4096 (b), N=64 over h in [0,512), K=512. Writes h_new to d_out.
// ---------------------------------------------------------------------------
__global__ __launch_bounds__(256, 2) void gates_kernel(
    const float* __restrict__ x, const float* __restrict__ hidden,
    const float* __restrict__ w_ih, const float* __restrict__ w_hh,
    const float* __restrict__ b_ih, const float* __restrict__ b_hh,
    float* __restrict__ dout)
{
    __shared__ float Axs[32 * 64];
    __shared__ float Ahs[32 * 64];
    __shared__ float Bsh[6][32 * 64];
    const int tid = threadIdx.x;
    const int b0 = blockIdx.x * 64;
    const int n0 = blockIdx.y * 64;
    const int tm = (tid & 15) * 4;
    const int tn = (tid >> 4) * 4;

    float acc[6][4][4] = {};

    for (int kc = 0; kc < Hn; kc += 32) {
        __syncthreads();
#pragma unroll
        for (int i = 0; i < 2; ++i) {
            int f = tid + i * 256;
            int row = f >> 3, kk4 = (f & 7) * 4;
            float4 vx = *(const float4*)(x + (size_t)(b0 + row) * Hn + kc + kk4);
            float4 vh = *(const float4*)(hidden + (size_t)(b0 + row) * Hn + kc + kk4);
            Axs[(kk4 + 0) * 64 + row] = vx.x;
            Axs[(kk4 + 1) * 64 + row] = vx.y;
            Axs[(kk4 + 2) * 64 + row] = vx.z;
            Axs[(kk4 + 3) * 64 + row] = vx.w;
            Ahs[(kk4 + 0) * 64 + row] = vh.x;
            Ahs[(kk4 + 1) * 64 + row] = vh.y;
            Ahs[(kk4 + 2) * 64 + row] = vh.z;
            Ahs[(kk4 + 3) * 64 + row] = vh.w;
        }
#pragma unroll
        for (int g = 0; g < 6; ++g) {
            const float* w = (g < 3) ? w_ih : w_hh;
            const int gr = (g % 3) * Hn;
#pragma unroll
            for (int i = 0; i < 2; ++i) {
                int f = tid + i * 256;
                int row = f >> 3, kk4 = (f & 7) * 4;
                float4 v = *(const float4*)(w + (size_t)(gr + n0 + row) * Hn + kc + kk4);
                Bsh[g][(kk4 + 0) * 64 + row] = v.x;
                Bsh[g][(kk4 + 1) * 64 + row] = v.y;
                Bsh[g][(kk4 + 2) * 64 + row] = v.z;
                Bsh[g][(kk4 + 3) * 64 + row] = v.w;
            }
        }
        __syncthreads();
#pragma unroll
        for (int kk = 0; kk < 32; ++kk) {
            float4 AX = *(const float4*)&Axs[kk * 64 + tm];
            float4 AH = *(const float4*)&Ahs[kk * 64 + tm];
            float ax[4] = {AX.x, AX.y, AX.z, AX.w};
            float ah[4] = {AH.x, AH.y, AH.z, AH.w};
#pragma unroll
            for (int g = 0; g < 6; ++g) {
                float4 Bv = *(const float4*)&Bsh[g][kk * 64 + tn];
                float bb[4] = {Bv.x, Bv.y, Bv.z, Bv.w};
#pragma unroll
                for (int r = 0; r < 4; ++r)
#pragma unroll
                    for (int j = 0; j < 4; ++j)
                        acc[g][r][j] += ((g < 3) ? ax[r] : ah[r]) * bb[j];
            }
        }
    }

    const int n = n0 + tn;
    float4 t;
    float bihr[4], bihz[4], bihn[4], bhhr[4], bhhz[4], bhhn[4];
    t = *(const float4*)&b_ih[n];            bihr[0]=t.x; bihr[1]=t.y; bihr[2]=t.z; bihr[3]=t.w;
    t = *(const float4*)&b_ih[Hn + n];       bihz[0]=t.x; bihz[1]=t.y; bihz[2]=t.z; bihz[3]=t.w;
    t = *(const float4*)&b_ih[2 * Hn + n];   bihn[0]=t.x; bihn[1]=t.y; bihn[2]=t.z; bihn[3]=t.w;
    t = *(const float4*)&b_hh[n];            bhhr[0]=t.x; bhhr[1]=t.y; bhhr[2]=t.z; bhhr[3]=t.w;
    t = *(const float4*)&b_hh[Hn + n];       bhhz[0]=t.x; bhhz[1]=t.y; bhhz[2]=t.z; bhhz[3]=t.w;
    t = *(const float4*)&b_hh[2 * Hn + n];   bhhn[0]=t.x; bhhn[1]=t.y; bhhn[2]=t.z; bhhn[3]=t.w;

#pragma unroll
    for (int r = 0; r < 4; ++r) {
        const int b = b0 + tm + r;
        float4 H0 = *(const float4*)&hidden[(size_t)b * Hn + n];
        float h0a[4] = {H0.x, H0.y, H0.z, H0.w};
        float o[4];
#pragma unroll
        for (int j = 0; j < 4; ++j) {
            float pre_r = acc[0][r][j] + bihr[j] + acc[3][r][j] + bhhr[j];
            float pre_z = acc[1][r][j] + bihz[j] + acc[4][r][j] + bhhz[j];
            float rg = sigmoidf_(pre_r);
            float zg = sigmoidf_(pre_z);
            float hnk = acc[5][r][j] + bhhn[j];
            float ng = tanhf(acc[2][r][j] + bihn[j] + rg * hnk);
            o[j] = (1.f - zg) * ng + zg * h0a[j];
        }
        float4 c = {o[0], o[1], o[2], o[3]};
        *(float4*)&dout[HNEW_OFF + (size_t)b * Hn + n] = c;
    }
}

// ---------------------------------------------------------------------------
// Kernel E: out = h_new @ out_W^T + out_b.  M=4096 N=64 K=512.
// BM=32, BN=64, BK=32, 2x4 thread tile.
// ---------------------------------------------------------------------------
__global__ __launch_bounds__(256) void out_kernel(
    const float* __restrict__ hnew, const float* __restrict__ out_W,
    const float* __restrict__ out_b, float* __restrict__ dout)
{
    __shared__ float As[32 * 32];  // [k][m]
    __shared__ float Bs[32 * 64];  // [k][n]
    const int tid = threadIdx.x;
    const int b0 = blockIdx.x * 32;
    const int tm = (tid & 15) * 2;
    const int tn = (tid >> 4) * 4;

    float acc[2][4] = {};

    for (int kc = 0; kc < Hn; kc += 32) {
        __syncthreads();
        {
            int row = tid >> 3, kk4 = (tid & 7) * 4;
            float4 v = *(const float4*)(hnew + (size_t)(b0 + row) * Hn + kc + kk4);
            As[(kk4 + 0) * 32 + row] = v.x;
            As[(kk4 + 1) * 32 + row] = v.y;
            As[(kk4 + 2) * 32 + row] = v.z;
            As[(kk4 + 3) * 32 + row] = v.w;
        }
#pragma unroll
        for (int i = 0; i < 2; ++i) {
            int f = tid + i * 256;
            int row = f >> 3, kk4 = (f & 7) * 4;
            float4 v = *(const float4*)(out_W + (size_t)row * Hn + kc + kk4);
            Bs[(kk4 + 0) * 64 + row] = v.x;
            Bs[(kk4 + 1) * 64 + row] = v.y;
            Bs[(kk4 + 2) * 64 + row] = v.z;
            Bs[(kk4 + 3) * 64 + row] = v.w;
        }
        __syncthreads();
#pragma unroll
        for (int kk = 0; kk < 32; ++kk) {
            float a0 = As[kk * 32 + tm];
            float a1 = As[kk * 32 + tm + 1];
            float4 Bv = *(const float4*)&Bs[kk * 64 + tn];
            float bb[4] = {Bv.x, Bv.y, Bv.z, Bv.w};
#pragma unroll
            for (int j = 0; j < 4; ++j) {
                acc[0][j] += a0 * bb[j];
                acc[1][j] += a1 * bb[j];
            }
        }
    }

    float4 ob = *(const float4*)&out_b[tn];
    float oba[4] = {ob.x, ob.y, ob.z, ob.w};
#pragma unroll
    for (int r = 0; r < 2; ++r) {
        int b = b0 + tm + r;
        float4 c = {acc[r][0] + oba[0], acc[r][1] + oba[1],
                    acc[r][2] + oba[2], acc[r][3] + oba[3]};
        *(float4*)&dout[(size_t)b * On + tn] = c;
    }
}

// ---------------------------------------------------------------------------
extern "C" void kernel_launch(void* const* d_in, const int* in_sizes, int n_in,
                              void* d_out, int out_size, void* d_ws, size_t ws_size,
                              hipStream_t stream)
{
    const float* last_input = (const float*)d_in[0];
    const float* hidden     = (const float*)d_in[1];
    const float* enc        = (const float*)d_in[2];
    const float* attn_W     = (const float*)d_in[3];
    const float* attn_b     = (const float*)d_in[4];
    const float* comb_W     = (const float*)d_in[5];
    const float* comb_b     = (const float*)d_in[6];
    const float* w_ih       = (const float*)d_in[7];
    const float* w_hh       = (const float*)d_in[8];
    const float* b_ih       = (const float*)d_in[9];
    const float* b_hh       = (const float*)d_in[10];
    const float* out_W      = (const float*)d_in[11];
    const float* out_b      = (const float*)d_in[12];

    float* out = (float*)d_out;
    float* ws  = (float*)d_ws;
    float* attnA = ws;                       // [B,H]
    float* x     = ws + (size_t)Bn * Hn;     // [B,H]

    attn_scores_kernel<<<Bn / 8, 256, 0, stream>>>(last_input, hidden, attn_W, attn_b, out);
    attn_apply_kernel<<<Bn / 4, 256, 0, stream>>>(enc, out + AW_OFF, attnA);
    comb_kernel<<<dim3(Bn / 128, Hn / 64), 256, 0, stream>>>(last_input, attnA, comb_W, comb_b, x);
    gates_kernel<<<dim3(Bn / 64, Hn / 64), 256, 0, stream>>>(x, hidden, w_ih, w_hh, b_ih, b_hh, out);
    out_kernel<<<Bn / 32, 256, 0, stream>>>(out + HNEW_OFF, out_W, out_b, out);
}

// Round 2
// 454.931 us; speedup vs baseline: 1.6547x; 1.6547x over previous
//
#include <hip/hip_runtime.h>
#include <cstddef>

constexpr int Bn = 4096;
constexpr int Sn = 200;
constexpr int Hn = 512;
constexpr int On = 64;
constexpr int K1 = 576; // Hn + On

constexpr size_t HNEW_OFF = (size_t)Bn * On;
constexpr size_t AW_OFF   = (size_t)Bn * On + (size_t)Bn * Hn;

// ---- ws layout (bytes); total ~46.3 MB ----
constexpr size_t CAT2B_OFF = 0;                                   // [4096][576] bf16
constexpr size_t XB_OFF    = CAT2B_OFF + (size_t)Bn * K1 * 2;     // [4096][512] bf16
constexpr size_t HB_OFF    = XB_OFF    + (size_t)Bn * Hn * 2;     // [4096][512] bf16
constexpr size_t WIHB_OFF  = HB_OFF    + (size_t)Bn * Hn * 2;     // [1536][512] bf16
constexpr size_t WHHB_OFF  = WIHB_OFF  + (size_t)3 * Hn * Hn * 2; // [1536][512] bf16
constexpr size_t CWB_OFF   = WHHB_OFF  + (size_t)3 * Hn * Hn * 2; // [512][576]  bf16
constexpr size_t OWB_OFF   = CWB_OFF   + (size_t)Hn * K1 * 2;     // [64][512]   bf16
constexpr size_t GIB_OFF   = OWB_OFF   + (size_t)On * Hn * 2;     // [4096][1536] bf16
constexpr size_t GHB_OFF   = GIB_OFF   + (size_t)Bn * 3 * Hn * 2; // [4096][1536] bf16
constexpr size_t HNB_OFF   = GHB_OFF   + (size_t)Bn * 3 * Hn * 2; // [4096][512] bf16

typedef __attribute__((ext_vector_type(8))) short bf16x8;
typedef __attribute__((ext_vector_type(4))) float f32x4;

__device__ __forceinline__ float sigmoidf_(float v) { return 1.f / (1.f + __expf(-v)); }
__device__ __forceinline__ unsigned short f2bf(float f) {
    unsigned u = __float_as_uint(f);
    return (unsigned short)((u + 0x7FFFu + ((u >> 16) & 1u)) >> 16);
}
__device__ __forceinline__ float bf2f(unsigned short b) {
    return __uint_as_float((unsigned)b << 16);
}

// ---------------------------------------------------------------------------
// fp32 -> bf16 converts: hidden, w_ih, w_hh, comb_W, out_W (one kernel)
// segments in 1024-elem blocks: 2048 | 768 | 768 | 288 | 32  => 3904 blocks
// ---------------------------------------------------------------------------
__global__ __launch_bounds__(256) void cvt_all_kernel(
    const float* __restrict__ hidden, const float* __restrict__ wih,
    const float* __restrict__ whh, const float* __restrict__ combW,
    const float* __restrict__ outW,
    unsigned short* __restrict__ hb, unsigned short* __restrict__ wihb,
    unsigned short* __restrict__ whhb, unsigned short* __restrict__ combWb,
    unsigned short* __restrict__ outWb)
{
    int blk = blockIdx.x;
    const float* src; unsigned short* dst; int base;
    if (blk < 2048)      { src = hidden; dst = hb;     base = blk; }
    else if (blk < 2816) { src = wih;    dst = wihb;   base = blk - 2048; }
    else if (blk < 3584) { src = whh;    dst = whhb;   base = blk - 2816; }
    else if (blk < 3872) { src = combW;  dst = combWb; base = blk - 3584; }
    else                 { src = outW;   dst = outWb;  base = blk - 3872; }
    size_t off = (size_t)base * 1024 + (size_t)threadIdx.x * 4;
    float4 v = *(const float4*)(src + off);
    ushort4 o = { f2bf(v.x), f2bf(v.y), f2bf(v.z), f2bf(v.w) };
    *(ushort4*)(dst + off) = o;
}

// last_input -> cat2b[:, 0:64] (bf16, row stride 576)
__global__ __launch_bounds__(256) void cvt_li_kernel(
    const float* __restrict__ li, unsigned short* __restrict__ cat2b)
{
    int gid = blockIdx.x * 256 + threadIdx.x;  // 65536 threads x 4 elems
    int b = gid >> 4;
    int j = (gid & 15) * 4;
    float4 v = *(const float4*)(li + (size_t)b * On + j);
    ushort4 o = { f2bf(v.x), f2bf(v.y), f2bf(v.z), f2bf(v.w) };
    *(ushort4*)(cat2b + (size_t)b * K1 + j) = o;
}

// ---------------------------------------------------------------------------
// Kernel A: scores = softmax([last_input | h0] @ attn_W^T + attn_b)  (fp32)
// ---------------------------------------------------------------------------
__global__ __launch_bounds__(256) void attn_scores_kernel(
    const float* __restrict__ last_input, const float* __restrict__ hidden,
    const float* __restrict__ attn_W, const float* __restrict__ attn_b,
    float* __restrict__ dout)
{
    __shared__ float cat1[8 * K1];
    __shared__ float red[4];
    const int tid = threadIdx.x;
    const int b0 = blockIdx.x * 8;

    for (int idx = tid; idx < 8 * K1; idx += 256) {
        int r = idx / K1, k = idx - r * K1;
        float v = (k < On) ? last_input[(size_t)(b0 + r) * On + k]
                           : hidden[(size_t)(b0 + r) * Hn + (k - On)];
        cat1[idx] = v;
    }
    __syncthreads();

    const int s = tid;
    float acc[8];
#pragma unroll
    for (int r = 0; r < 8; ++r) acc[r] = 0.f;

    if (s < Sn) {
        const float4* wp = (const float4*)(attn_W + (size_t)s * K1);
#pragma unroll 4
        for (int k4 = 0; k4 < K1 / 4; ++k4) {
            float4 w4 = wp[k4];
#pragma unroll
            for (int r = 0; r < 8; ++r) {
                float4 a4 = *(const float4*)&cat1[r * K1 + k4 * 4];
                acc[r] += w4.x * a4.x + w4.y * a4.y + w4.z * a4.z + w4.w * a4.w;
            }
        }
        float bb = attn_b[s];
#pragma unroll
        for (int r = 0; r < 8; ++r) acc[r] += bb;
    }

    const int lane = tid & 63, wid = tid >> 6;
    for (int r = 0; r < 8; ++r) {
        float v = (s < Sn) ? acc[r] : -3.0e38f;
#pragma unroll
        for (int o = 32; o > 0; o >>= 1) v = fmaxf(v, __shfl_xor(v, o, 64));
        if (lane == 0) red[wid] = v;
        __syncthreads();
        float m = fmaxf(fmaxf(red[0], red[1]), fmaxf(red[2], red[3]));
        __syncthreads();
        float e = (s < Sn) ? __expf(acc[r] - m) : 0.f;
        float t = e;
#pragma unroll
        for (int o = 32; o > 0; o >>= 1) t += __shfl_xor(t, o, 64);
        if (lane == 0) red[wid] = t;
        __syncthreads();
        float sum = red[0] + red[1] + red[2] + red[3];
        __syncthreads();
        if (s < Sn) dout[AW_OFF + (size_t)(b0 + r) * Sn + s] = e / sum;
    }
}

// ---------------------------------------------------------------------------
// Kernel B: attn_applied[b,h] = sum_s w[b,s]*enc[s,b,h] -> cat2b[:,64:] bf16
// ---------------------------------------------------------------------------
__global__ __launch_bounds__(256) void attn_apply_kernel(
    const float* __restrict__ enc, const float* __restrict__ aw,
    unsigned short* __restrict__ cat2b)
{
    __shared__ float wl[4 * Sn];
    const int tid = threadIdx.x;
    const int b0 = blockIdx.x * 4;

    for (int idx = tid; idx < 4 * Sn; idx += 256)
        wl[idx] = aw[(size_t)b0 * Sn + idx];
    __syncthreads();

    const int bi0 = tid >> 7;
    const int bi1 = bi0 + 2;
    float4 acc0 = {0, 0, 0, 0}, acc1 = {0, 0, 0, 0};

#pragma unroll 4
    for (int s = 0; s < Sn; ++s) {
        const float4* p = (const float4*)(enc + ((size_t)s * Bn + b0) * Hn);
        float4 v0 = p[tid];
        float4 v1 = p[tid + 256];
        float w0 = wl[bi0 * Sn + s];
        float w1 = wl[bi1 * Sn + s];
        acc0.x += w0 * v0.x; acc0.y += w0 * v0.y; acc0.z += w0 * v0.z; acc0.w += w0 * v0.w;
        acc1.x += w1 * v1.x; acc1.y += w1 * v1.y; acc1.z += w1 * v1.z; acc1.w += w1 * v1.w;
    }
    const int h = (tid & 127) * 4;
    ushort4 o0 = { f2bf(acc0.x), f2bf(acc0.y), f2bf(acc0.z), f2bf(acc0.w) };
    ushort4 o1 = { f2bf(acc1.x), f2bf(acc1.y), f2bf(acc1.z), f2bf(acc1.w) };
    *(ushort4*)(cat2b + (size_t)(b0 + bi0) * K1 + On + h) = o0;
    *(ushort4*)(cat2b + (size_t)(b0 + bi1) * K1 + On + h) = o1;
}

// ---------------------------------------------------------------------------
// MFMA GEMM: C[M][N] = A[M][K]bf16 @ B[N][K]bf16^T + bias, opt ReLU,
// out fp32 or bf16. 4 waves (2x2), wave-tile (MF*16)x(NF*16), BK=64,
// XOR-swizzled LDS ((row&7)<<4), both-sides-consistent (rule 21).
// ---------------------------------------------------------------------------
template<int MF, int NF, bool RELU, bool OUT_BF16>
__global__ __launch_bounds__(256, 2) void gemm_bt_kernel(
    const unsigned short* __restrict__ A, const unsigned short* __restrict__ B,
    const float* __restrict__ bias, float* __restrict__ Cf,
    unsigned short* __restrict__ Cb, int K, int ldc)
{
    constexpr int BM = 32 * MF;
    constexpr int BN = 32 * NF;
    __shared__ unsigned short As[BM * 64];
    __shared__ unsigned short Bs[BN * 64];

    const int tid = threadIdx.x;
    const int m0 = blockIdx.x * BM;
    const int n0 = blockIdx.y * BN;
    const int wave = tid >> 6;
    const int lane = tid & 63;
    const int wm = wave >> 1, wn = wave & 1;
    const int l15 = lane & 15, lg = lane >> 4;

    f32x4 acc[MF][NF];
#pragma unroll
    for (int i = 0; i < MF; ++i)
#pragma unroll
        for (int j = 0; j < NF; ++j) acc[i][j] = (f32x4){0.f, 0.f, 0.f, 0.f};

    for (int kc = 0; kc < K; kc += 64) {
        __syncthreads();
#pragma unroll
        for (int i = 0; i < BM * 8 / 256; ++i) {
            int idx = tid + i * 256;
            int row = idx >> 3, ck = idx & 7;
            uint4 v = *(const uint4*)(A + (size_t)(m0 + row) * K + kc + ck * 8);
            int byte = row * 128 + ((ck * 16) ^ ((row & 7) << 4));
            *(uint4*)((char*)As + byte) = v;
        }
#pragma unroll
        for (int i = 0; i < BN * 8 / 256; ++i) {
            int idx = tid + i * 256;
            int row = idx >> 3, ck = idx & 7;
            uint4 v = *(const uint4*)(B + (size_t)(n0 + row) * K + kc + ck * 8);
            int byte = row * 128 + ((ck * 16) ^ ((row & 7) << 4));
            *(uint4*)((char*)Bs + byte) = v;
        }
        __syncthreads();
#pragma unroll
        for (int s = 0; s < 2; ++s) {
            bf16x8 af[MF], bfr[NF];
#pragma unroll
            for (int i = 0; i < MF; ++i) {
                int row = wm * (MF * 16) + i * 16 + l15;
                int byte = row * 128 + ((s * 64 + lg * 16) ^ ((row & 7) << 4));
                af[i] = *(const bf16x8*)((const char*)As + byte);
            }
#pragma unroll
            for (int j = 0; j < NF; ++j) {
                int row = wn * (NF * 16) + j * 16 + l15;
                int byte = row * 128 + ((s * 64 + lg * 16) ^ ((row & 7) << 4));
                bfr[j] = *(const bf16x8*)((const char*)Bs + byte);
            }
#pragma unroll
            for (int i = 0; i < MF; ++i)
#pragma unroll
                for (int j = 0; j < NF; ++j)
                    acc[i][j] = __builtin_amdgcn_mfma_f32_16x16x32_bf16(
                        af[i], bfr[j], acc[i][j], 0, 0, 0);
        }
    }

#pragma unroll
    for (int i = 0; i < MF; ++i) {
        int m = m0 + wm * (MF * 16) + i * 16 + lg * 4;
#pragma unroll
        for (int j = 0; j < NF; ++j) {
            int n = n0 + wn * (NF * 16) + j * 16 + l15;
            float bv = bias[n];
#pragma unroll
            for (int r = 0; r < 4; ++r) {
                float v = acc[i][j][r] + bv;
                if (RELU) v = fmaxf(v, 0.f);
                if (OUT_BF16) Cb[(size_t)(m + r) * ldc + n] = f2bf(v);
                else          Cf[(size_t)(m + r) * ldc + n] = v;
            }
        }
    }
}

// ---------------------------------------------------------------------------
// GRU elementwise: h_new = (1-z)*n + z*h0  (biases folded into gi/gh GEMMs)
// ---------------------------------------------------------------------------
__global__ __launch_bounds__(256) void gru_elem_kernel(
    const unsigned short* __restrict__ gib, const unsigned short* __restrict__ ghb,
    const float* __restrict__ hidden, float* __restrict__ dout,
    unsigned short* __restrict__ hnewb)
{
    int gid = blockIdx.x * 256 + threadIdx.x;  // 524288 threads x 4 cols
    int b = gid >> 7;
    int n = (gid & 127) * 4;
    const unsigned short* gi = gib + (size_t)b * (3 * Hn);
    const unsigned short* gh = ghb + (size_t)b * (3 * Hn);
    ushort4 ir = *(const ushort4*)(gi + n);
    ushort4 iz = *(const ushort4*)(gi + Hn + n);
    ushort4 in_ = *(const ushort4*)(gi + 2 * Hn + n);
    ushort4 hr = *(const ushort4*)(gh + n);
    ushort4 hz = *(const ushort4*)(gh + Hn + n);
    ushort4 hn = *(const ushort4*)(gh + 2 * Hn + n);
    float4 h0 = *(const float4*)(hidden + (size_t)b * Hn + n);

    float o[4], irv[4] = {bf2f(ir.x), bf2f(ir.y), bf2f(ir.z), bf2f(ir.w)};
    float izv[4] = {bf2f(iz.x), bf2f(iz.y), bf2f(iz.z), bf2f(iz.w)};
    float inv[4] = {bf2f(in_.x), bf2f(in_.y), bf2f(in_.z), bf2f(in_.w)};
    float hrv[4] = {bf2f(hr.x), bf2f(hr.y), bf2f(hr.z), bf2f(hr.w)};
    float hzv[4] = {bf2f(hz.x), bf2f(hz.y), bf2f(hz.z), bf2f(hz.w)};
    float hnv[4] = {bf2f(hn.x), bf2f(hn.y), bf2f(hn.z), bf2f(hn.w)};
    float h0v[4] = {h0.x, h0.y, h0.z, h0.w};
#pragma unroll
    for (int j = 0; j < 4; ++j) {
        float rg = sigmoidf_(irv[j] + hrv[j]);
        float zg = sigmoidf_(izv[j] + hzv[j]);
        float ng = tanhf(inv[j] + rg * hnv[j]);
        o[j] = (1.f - zg) * ng + zg * h0v[j];
    }
    float4 c = {o[0], o[1], o[2], o[3]};
    *(float4*)&dout[HNEW_OFF + (size_t)b * Hn + n] = c;
    ushort4 ob = { f2bf(o[0]), f2bf(o[1]), f2bf(o[2]), f2bf(o[3]) };
    *(ushort4*)(hnewb + (size_t)b * Hn + n) = ob;
}

// ---------------------------------------------------------------------------
extern "C" void kernel_launch(void* const* d_in, const int* in_sizes, int n_in,
                              void* d_out, int out_size, void* d_ws, size_t ws_size,
                              hipStream_t stream)
{
    const float* last_input = (const float*)d_in[0];
    const float* hidden     = (const float*)d_in[1];
    const float* enc        = (const float*)d_in[2];
    const float* attn_W     = (const float*)d_in[3];
    const float* attn_b     = (const float*)d_in[4];
    const float* comb_W     = (const float*)d_in[5];
    const float* comb_b     = (const float*)d_in[6];
    const float* w_ih       = (const float*)d_in[7];
    const float* w_hh       = (const float*)d_in[8];
    const float* b_ih       = (const float*)d_in[9];
    const float* b_hh       = (const float*)d_in[10];
    const float* out_W      = (const float*)d_in[11];
    const float* out_b      = (const float*)d_in[12];

    float* out = (float*)d_out;
    char*  ws  = (char*)d_ws;
    unsigned short* cat2b  = (unsigned short*)(ws + CAT2B_OFF);
    unsigned short* xb     = (unsigned short*)(ws + XB_OFF);
    unsigned short* hb     = (unsigned short*)(ws + HB_OFF);
    unsigned short* wihb   = (unsigned short*)(ws + WIHB_OFF);
    unsigned short* whhb   = (unsigned short*)(ws + WHHB_OFF);
    unsigned short* combWb = (unsigned short*)(ws + CWB_OFF);
    unsigned short* outWb  = (unsigned short*)(ws + OWB_OFF);
    unsigned short* gib    = (unsigned short*)(ws + GIB_OFF);
    unsigned short* ghb    = (unsigned short*)(ws + GHB_OFF);
    unsigned short* hnewb  = (unsigned short*)(ws + HNB_OFF);

    attn_scores_kernel<<<Bn / 8, 256, 0, stream>>>(last_input, hidden, attn_W, attn_b, out);
    cvt_all_kernel<<<3904, 256, 0, stream>>>(hidden, w_ih, w_hh, comb_W, out_W,
                                             hb, wihb, whhb, combWb, outWb);
    cvt_li_kernel<<<256, 256, 0, stream>>>(last_input, cat2b);
    attn_apply_kernel<<<Bn / 4, 256, 0, stream>>>(enc, out + AW_OFF, cat2b);

    // comb: x = relu(cat2b @ comb_W^T + comb_b) -> xb (bf16)
    gemm_bt_kernel<4, 4, true, true><<<dim3(Bn / 128, Hn / 128), 256, 0, stream>>>(
        cat2b, combWb, comb_b, nullptr, xb, K1, Hn);
    // gi = xb @ w_ih^T + b_ih -> gib (bf16)
    gemm_bt_kernel<4, 4, false, true><<<dim3(Bn / 128, 3 * Hn / 128), 256, 0, stream>>>(
        xb, wihb, b_ih, nullptr, gib, Hn, 3 * Hn);
    // gh = hb @ w_hh^T + b_hh -> ghb (bf16)
    gemm_bt_kernel<4, 4, false, true><<<dim3(Bn / 128, 3 * Hn / 128), 256, 0, stream>>>(
        hb, whhb, b_hh, nullptr, ghb, Hn, 3 * Hn);
    // GRU elementwise -> h_new (fp32, d_out) + hnewb (bf16)
    gru_elem_kernel<<<2048, 256, 0, stream>>>(gib, ghb, hidden, out, hnewb);
    // out = hnewb @ out_W^T + out_b -> d_out[0:] (fp32)
    gemm_bt_kernel<4, 2, false, false><<<dim3(Bn / 128, 1), 256, 0, stream>>>(
        hnewb, outWb, out_b, out, nullptr, Hn, On);
}

// Round 3
// 329.273 us; speedup vs baseline: 2.2862x; 1.3816x over previous
//
#include <hip/hip_runtime.h>
#include <cstddef>

constexpr int Bn = 4096;
constexpr int Sn = 200;
constexpr int Hn = 512;
constexpr int On = 64;
constexpr int K1 = 576; // Hn + On

constexpr size_t HNEW_OFF = (size_t)Bn * On;
constexpr size_t AW_OFF   = (size_t)Bn * On + (size_t)Bn * Hn;

// ---- ws layout (bytes) ----
constexpr size_t CAT1B_OFF = 0;                                    // [4096][576] bf16: [li | hidden]
constexpr size_t CAT2B_OFF = CAT1B_OFF + (size_t)Bn * K1 * 2;      // [4096][576] bf16: [li | attnA]
constexpr size_t XB_OFF    = CAT2B_OFF + (size_t)Bn * K1 * 2;      // [4096][512] bf16
constexpr size_t WIHB_OFF  = XB_OFF    + (size_t)Bn * Hn * 2;      // [1536][512] bf16
constexpr size_t WHHB_OFF  = WIHB_OFF  + (size_t)3 * Hn * Hn * 2;  // [1536][512] bf16
constexpr size_t CWB_OFF   = WHHB_OFF  + (size_t)3 * Hn * Hn * 2;  // [512][576]  bf16
constexpr size_t OWB_OFF   = CWB_OFF   + (size_t)Hn * K1 * 2;      // [64][512]   bf16
constexpr size_t AWB_OFF   = OWB_OFF   + (size_t)On * Hn * 2;      // [256][576]  bf16 (padded attn_W)
constexpr size_t LOG_OFF   = AWB_OFF   + (size_t)256 * K1 * 2;     // [4096][200] fp32 logits
constexpr size_t GIB_OFF   = LOG_OFF   + (size_t)Bn * Sn * 4;      // [4096][1536] bf16
constexpr size_t GHB_OFF   = GIB_OFF   + (size_t)Bn * 3 * Hn * 2;  // [4096][1536] bf16
constexpr size_t HNB_OFF   = GHB_OFF   + (size_t)Bn * 3 * Hn * 2;  // [4096][512] bf16

typedef __attribute__((ext_vector_type(8))) short bf16x8;
typedef __attribute__((ext_vector_type(4))) float f32x4;

__device__ __forceinline__ float sigmoidf_(float v) { return 1.f / (1.f + __expf(-v)); }
__device__ __forceinline__ unsigned short f2bf(float f) {
    unsigned u = __float_as_uint(f);
    return (unsigned short)((u + 0x7FFFu + ((u >> 16) & 1u)) >> 16);
}
__device__ __forceinline__ float bf2f(unsigned short b) {
    return __uint_as_float((unsigned)b << 16);
}
__device__ __forceinline__ ushort4 pack4(float4 v) {
    ushort4 o = { f2bf(v.x), f2bf(v.y), f2bf(v.z), f2bf(v.w) };
    return o;
}

// ---------------------------------------------------------------------------
// One fused convert kernel. 1024-elem blocks, segment map:
//  [0,2048)      hidden   -> cat1b cols 64:576
//  [2048,2816)   w_ih     -> wihb (linear)
//  [2816,3584)   w_hh     -> whhb (linear)
//  [3584,3872)   comb_W   -> combWb (linear)
//  [3872,3904)   out_W    -> outWb (linear)
//  [3904,4017)   attn_W   -> awWb rows 0:200 (linear, guarded)
//  [4017,4049)   zero     -> awWb rows 200:256 (guarded)
//  [4049,4305)   last_in  -> cat1b & cat2b cols 0:64
// ---------------------------------------------------------------------------
__global__ __launch_bounds__(256) void cvt_all_kernel(
    const float* __restrict__ hidden, const float* __restrict__ wih,
    const float* __restrict__ whh, const float* __restrict__ combW,
    const float* __restrict__ outW, const float* __restrict__ attnW,
    const float* __restrict__ li,
    unsigned short* __restrict__ cat1b, unsigned short* __restrict__ cat2b,
    unsigned short* __restrict__ wihb, unsigned short* __restrict__ whhb,
    unsigned short* __restrict__ combWb, unsigned short* __restrict__ outWb,
    unsigned short* __restrict__ awWb)
{
    const int blk = blockIdx.x;
    const int t = threadIdx.x;
    if (blk < 2048) {
        size_t off = (size_t)blk * 1024 + (size_t)t * 4;
        int b = (int)(off >> 9), col = (int)(off & 511);
        float4 v = *(const float4*)(hidden + off);
        *(ushort4*)(cat1b + (size_t)b * K1 + On + col) = pack4(v);
    } else if (blk < 3584) {
        size_t off = (size_t)(blk - 2048) * 1024 + (size_t)t * 4;
        const float* s = (blk < 2816) ? wih : whh;
        unsigned short* d = (blk < 2816) ? wihb : whhb;
        if (blk >= 2816) off -= (size_t)768 * 1024;
        float4 v = *(const float4*)(s + off);
        *(ushort4*)(d + off) = pack4(v);
    } else if (blk < 3872) {
        size_t off = (size_t)(blk - 3584) * 1024 + (size_t)t * 4;
        float4 v = *(const float4*)(combW + off);
        *(ushort4*)(combWb + off) = pack4(v);
    } else if (blk < 3904) {
        size_t off = (size_t)(blk - 3872) * 1024 + (size_t)t * 4;
        float4 v = *(const float4*)(outW + off);
        *(ushort4*)(outWb + off) = pack4(v);
    } else if (blk < 4017) {
        size_t off = (size_t)(blk - 3904) * 1024 + (size_t)t * 4;
        if (off < (size_t)Sn * K1) {
            float4 v = *(const float4*)(attnW + off);
            *(ushort4*)(awWb + off) = pack4(v);
        }
    } else if (blk < 4049) {
        size_t off = (size_t)Sn * K1 + (size_t)(blk - 4017) * 1024 + (size_t)t * 4;
        if (off < (size_t)256 * K1) {
            ushort4 z = {0, 0, 0, 0};
            *(ushort4*)(awWb + off) = z;
        }
    } else {
        size_t off = (size_t)(blk - 4049) * 1024 + (size_t)t * 4;
        int b = (int)(off >> 6), col = (int)(off & 63);
        float4 v = *(const float4*)(li + off);
        ushort4 o = pack4(v);
        *(ushort4*)(cat1b + (size_t)b * K1 + col) = o;
        *(ushort4*)(cat2b + (size_t)b * K1 + col) = o;
    }
}

// ---------------------------------------------------------------------------
// MFMA GEMM body: C[M][N] = A[M][K]bf16(lda) @ B[N][K]bf16^T + bias
// 4 waves (2x2), BK=64, XOR-swizzled LDS, epilogue masked to n<nmax.
// ---------------------------------------------------------------------------
template<int MF, int NF, bool RELU, bool OUT_BF16>
__device__ __forceinline__ void gemm_bt_body(
    const unsigned short* __restrict__ A, int lda,
    const unsigned short* __restrict__ B,
    const float* __restrict__ bias, float* __restrict__ Cf,
    unsigned short* __restrict__ Cb, int K, int ldc,
    int m0, int n0, int nmax)
{
    constexpr int BM = 32 * MF;
    constexpr int BN = 32 * NF;
    __shared__ unsigned short As[BM * 64];
    __shared__ unsigned short Bs[BN * 64];

    const int tid = threadIdx.x;
    const int wave = tid >> 6;
    const int lane = tid & 63;
    const int wm = wave >> 1, wn = wave & 1;
    const int l15 = lane & 15, lg = lane >> 4;

    f32x4 acc[MF][NF];
#pragma unroll
    for (int i = 0; i < MF; ++i)
#pragma unroll
        for (int j = 0; j < NF; ++j) acc[i][j] = (f32x4){0.f, 0.f, 0.f, 0.f};

    for (int kc = 0; kc < K; kc += 64) {
        __syncthreads();
#pragma unroll
        for (int i = 0; i < BM * 8 / 256; ++i) {
            int idx = tid + i * 256;
            int row = idx >> 3, ck = idx & 7;
            uint4 v = *(const uint4*)(A + (size_t)(m0 + row) * lda + kc + ck * 8);
            int byte = row * 128 + ((ck * 16) ^ ((row & 7) << 4));
            *(uint4*)((char*)As + byte) = v;
        }
#pragma unroll
        for (int i = 0; i < BN * 8 / 256; ++i) {
            int idx = tid + i * 256;
            int row = idx >> 3, ck = idx & 7;
            uint4 v = *(const uint4*)(B + (size_t)(n0 + row) * K + kc + ck * 8);
            int byte = row * 128 + ((ck * 16) ^ ((row & 7) << 4));
            *(uint4*)((char*)Bs + byte) = v;
        }
        __syncthreads();
#pragma unroll
        for (int s = 0; s < 2; ++s) {
            bf16x8 af[MF], bfr[NF];
#pragma unroll
            for (int i = 0; i < MF; ++i) {
                int row = wm * (MF * 16) + i * 16 + l15;
                int byte = row * 128 + ((s * 64 + lg * 16) ^ ((row & 7) << 4));
                af[i] = *(const bf16x8*)((const char*)As + byte);
            }
#pragma unroll
            for (int j = 0; j < NF; ++j) {
                int row = wn * (NF * 16) + j * 16 + l15;
                int byte = row * 128 + ((s * 64 + lg * 16) ^ ((row & 7) << 4));
                bfr[j] = *(const bf16x8*)((const char*)Bs + byte);
            }
#pragma unroll
            for (int i = 0; i < MF; ++i)
#pragma unroll
                for (int j = 0; j < NF; ++j)
                    acc[i][j] = __builtin_amdgcn_mfma_f32_16x16x32_bf16(
                        af[i], bfr[j], acc[i][j], 0, 0, 0);
        }
    }

#pragma unroll
    for (int i = 0; i < MF; ++i) {
        int m = m0 + wm * (MF * 16) + i * 16 + lg * 4;
#pragma unroll
        for (int j = 0; j < NF; ++j) {
            int n = n0 + wn * (NF * 16) + j * 16 + l15;
            if (n < nmax) {
                float bv = bias[n];
#pragma unroll
                for (int r = 0; r < 4; ++r) {
                    float v = acc[i][j][r] + bv;
                    if (RELU) v = fmaxf(v, 0.f);
                    if (OUT_BF16) Cb[(size_t)(m + r) * ldc + n] = f2bf(v);
                    else          Cf[(size_t)(m + r) * ldc + n] = v;
                }
            }
        }
    }
}

// scores: logits = cat1b @ awWb^T + attn_b.  M=4096 N=256(mask 200) K=576.
__global__ __launch_bounds__(256, 2) void scores_gemm_kernel(
    const unsigned short* __restrict__ cat1b, const unsigned short* __restrict__ awWb,
    const float* __restrict__ attn_b, float* __restrict__ logits)
{
    gemm_bt_body<2, 2, false, false>(cat1b, K1, awWb, attn_b, logits, nullptr,
                                     K1, Sn, blockIdx.x * 64, blockIdx.y * 64, Sn);
}

// comb: xb = relu(cat2b @ combWb^T + comb_b). M=4096 N=512 K=576.
__global__ __launch_bounds__(256, 2) void comb_gemm_kernel(
    const unsigned short* __restrict__ cat2b, const unsigned short* __restrict__ combWb,
    const float* __restrict__ comb_b, unsigned short* __restrict__ xb)
{
    gemm_bt_body<4, 4, true, true>(cat2b, K1, combWb, comb_b, nullptr, xb,
                                   K1, Hn, blockIdx.x * 128, blockIdx.y * 128, Hn);
}

// gates: y<12 -> gi = xb @ wihb^T + b_ih ; y>=12 -> gh = cat1b[:,64:] @ whhb^T + b_hh
__global__ __launch_bounds__(256, 2) void gates_gemm_kernel(
    const unsigned short* __restrict__ xb, const unsigned short* __restrict__ cat1b,
    const unsigned short* __restrict__ wihb, const unsigned short* __restrict__ whhb,
    const float* __restrict__ b_ih, const float* __restrict__ b_hh,
    unsigned short* __restrict__ gib, unsigned short* __restrict__ ghb)
{
    const int y = blockIdx.y;
    const bool is_gh = (y >= 12);
    const unsigned short* A = is_gh ? (cat1b + On) : xb;
    const int lda = is_gh ? K1 : Hn;
    const unsigned short* B = is_gh ? whhb : wihb;
    const float* bias = is_gh ? b_hh : b_ih;
    unsigned short* C = is_gh ? ghb : gib;
    const int n0 = (is_gh ? y - 12 : y) * 128;
    gemm_bt_body<4, 4, false, true>(A, lda, B, bias, nullptr, C,
                                    Hn, 3 * Hn, blockIdx.x * 128, n0, 3 * Hn);
}

// out: out = hnewb @ outWb^T + out_b. M=4096 N=64 K=512.
__global__ __launch_bounds__(256, 2) void out_gemm_kernel(
    const unsigned short* __restrict__ hnewb, const unsigned short* __restrict__ outWb,
    const float* __restrict__ out_b, float* __restrict__ dout)
{
    gemm_bt_body<4, 2, false, false>(hnewb, Hn, outWb, out_b, dout, nullptr,
                                     Hn, On, blockIdx.x * 128, 0, On);
}

// ---------------------------------------------------------------------------
// Row softmax over [4096][200]: one wave per row -> attn_weights in d_out.
// ---------------------------------------------------------------------------
__global__ __launch_bounds__(256) void softmax_kernel(
    const float* __restrict__ logits, float* __restrict__ dout)
{
    const int row = blockIdx.x * 4 + (threadIdx.x >> 6);
    const int lane = threadIdx.x & 63;
    const float* lp = logits + (size_t)row * Sn;
    float v[4], e[4];
    float m = -3.0e38f;
#pragma unroll
    for (int k = 0; k < 4; ++k) {
        int s = lane + 64 * k;
        v[k] = (s < Sn) ? lp[s] : -3.0e38f;
        m = fmaxf(m, v[k]);
    }
#pragma unroll
    for (int o = 32; o > 0; o >>= 1) m = fmaxf(m, __shfl_xor(m, o, 64));
    float sum = 0.f;
#pragma unroll
    for (int k = 0; k < 4; ++k) {
        int s = lane + 64 * k;
        e[k] = (s < Sn) ? __expf(v[k] - m) : 0.f;
        sum += e[k];
    }
#pragma unroll
    for (int o = 32; o > 0; o >>= 1) sum += __shfl_xor(sum, o, 64);
    float inv = 1.f / sum;
#pragma unroll
    for (int k = 0; k < 4; ++k) {
        int s = lane + 64 * k;
        if (s < Sn) dout[AW_OFF + (size_t)row * Sn + s] = e[k] * inv;
    }
}

// ---------------------------------------------------------------------------
// attn_applied[b,h] = sum_s w[b,s]*enc[s,b,h] -> cat2b[:,64:] bf16
// 8 b-rows/block, 4 nontemporal dwordx4 loads/thread/iter.
// ---------------------------------------------------------------------------
__global__ __launch_bounds__(256) void attn_apply_kernel(
    const float* __restrict__ enc, const float* __restrict__ aw,
    unsigned short* __restrict__ cat2b)
{
    __shared__ float wl[8 * Sn];
    const int tid = threadIdx.x;
    const int b0 = blockIdx.x * 8;

    for (int idx = tid; idx < 8 * Sn; idx += 256)
        wl[idx] = aw[(size_t)b0 * Sn + idx];
    __syncthreads();

    const int q = tid >> 7;          // 0/1: rows q*4 .. q*4+3
    const int hc = tid & 127;        // f32x4-chunk within the 512-col row
    const f32x4* base = (const f32x4*)enc + ((size_t)(b0 + q * 4)) * 128 + hc;

    f32x4 a0 = {0,0,0,0}, a1 = {0,0,0,0}, a2 = {0,0,0,0}, a3 = {0,0,0,0};

#pragma unroll 2
    for (int s = 0; s < Sn; ++s) {
        const f32x4* p = base + (size_t)s * (Bn * 128);
        f32x4 v0 = __builtin_nontemporal_load(p);
        f32x4 v1 = __builtin_nontemporal_load(p + 128);
        f32x4 v2 = __builtin_nontemporal_load(p + 256);
        f32x4 v3 = __builtin_nontemporal_load(p + 384);
        float w0 = wl[(q * 4 + 0) * Sn + s];
        float w1 = wl[(q * 4 + 1) * Sn + s];
        float w2 = wl[(q * 4 + 2) * Sn + s];
        float w3 = wl[(q * 4 + 3) * Sn + s];
        a0 += v0 * w0; a1 += v1 * w1; a2 += v2 * w2; a3 += v3 * w3;
    }

    const int h = hc * 4;
    f32x4 accs[4] = {a0, a1, a2, a3};
#pragma unroll
    for (int r = 0; r < 4; ++r) {
        ushort4 o = { f2bf(accs[r][0]), f2bf(accs[r][1]), f2bf(accs[r][2]), f2bf(accs[r][3]) };
        *(ushort4*)(cat2b + (size_t)(b0 + q * 4 + r) * K1 + On + h) = o;
    }
}

// ---------------------------------------------------------------------------
// GRU elementwise: h_new = (1-z)*n + z*h0 (biases folded into gi/gh)
// ---------------------------------------------------------------------------
__global__ __launch_bounds__(256) void gru_elem_kernel(
    const unsigned short* __restrict__ gib, const unsigned short* __restrict__ ghb,
    const float* __restrict__ hidden, float* __restrict__ dout,
    unsigned short* __restrict__ hnewb)
{
    int gid = blockIdx.x * 256 + threadIdx.x;
    int b = gid >> 7;
    int n = (gid & 127) * 4;
    const unsigned short* gi = gib + (size_t)b * (3 * Hn);
    const unsigned short* gh = ghb + (size_t)b * (3 * Hn);
    ushort4 ir = *(const ushort4*)(gi + n);
    ushort4 iz = *(const ushort4*)(gi + Hn + n);
    ushort4 in_ = *(const ushort4*)(gi + 2 * Hn + n);
    ushort4 hr = *(const ushort4*)(gh + n);
    ushort4 hz = *(const ushort4*)(gh + Hn + n);
    ushort4 hn = *(const ushort4*)(gh + 2 * Hn + n);
    float4 h0 = *(const float4*)(hidden + (size_t)b * Hn + n);

    float o[4], irv[4] = {bf2f(ir.x), bf2f(ir.y), bf2f(ir.z), bf2f(ir.w)};
    float izv[4] = {bf2f(iz.x), bf2f(iz.y), bf2f(iz.z), bf2f(iz.w)};
    float inv[4] = {bf2f(in_.x), bf2f(in_.y), bf2f(in_.z), bf2f(in_.w)};
    float hrv[4] = {bf2f(hr.x), bf2f(hr.y), bf2f(hr.z), bf2f(hr.w)};
    float hzv[4] = {bf2f(hz.x), bf2f(hz.y), bf2f(hz.z), bf2f(hz.w)};
    float hnv[4] = {bf2f(hn.x), bf2f(hn.y), bf2f(hn.z), bf2f(hn.w)};
    float h0v[4] = {h0.x, h0.y, h0.z, h0.w};
#pragma unroll
    for (int j = 0; j < 4; ++j) {
        float rg = sigmoidf_(irv[j] + hrv[j]);
        float zg = sigmoidf_(izv[j] + hzv[j]);
        float ng = tanhf(inv[j] + rg * hnv[j]);
        o[j] = (1.f - zg) * ng + zg * h0v[j];
    }
    float4 c = {o[0], o[1], o[2], o[3]};
    *(float4*)&dout[HNEW_OFF + (size_t)b * Hn + n] = c;
    ushort4 ob = { f2bf(o[0]), f2bf(o[1]), f2bf(o[2]), f2bf(o[3]) };
    *(ushort4*)(hnewb + (size_t)b * Hn + n) = ob;
}

// ---------------------------------------------------------------------------
extern "C" void kernel_launch(void* const* d_in, const int* in_sizes, int n_in,
                              void* d_out, int out_size, void* d_ws, size_t ws_size,
                              hipStream_t stream)
{
    const float* last_input = (const float*)d_in[0];
    const float* hidden     = (const float*)d_in[1];
    const float* enc        = (const float*)d_in[2];
    const float* attn_W     = (const float*)d_in[3];
    const float* attn_b     = (const float*)d_in[4];
    const float* comb_W     = (const float*)d_in[5];
    const float* comb_b     = (const float*)d_in[6];
    const float* w_ih       = (const float*)d_in[7];
    const float* w_hh       = (const float*)d_in[8];
    const float* b_ih       = (const float*)d_in[9];
    const float* b_hh       = (const float*)d_in[10];
    const float* out_W      = (const float*)d_in[11];
    const float* out_b      = (const float*)d_in[12];

    float* out = (float*)d_out;
    char*  ws  = (char*)d_ws;
    unsigned short* cat1b  = (unsigned short*)(ws + CAT1B_OFF);
    unsigned short* cat2b  = (unsigned short*)(ws + CAT2B_OFF);
    unsigned short* xb     = (unsigned short*)(ws + XB_OFF);
    unsigned short* wihb   = (unsigned short*)(ws + WIHB_OFF);
    unsigned short* whhb   = (unsigned short*)(ws + WHHB_OFF);
    unsigned short* combWb = (unsigned short*)(ws + CWB_OFF);
    unsigned short* outWb  = (unsigned short*)(ws + OWB_OFF);
    unsigned short* awWb   = (unsigned short*)(ws + AWB_OFF);
    float*          logits = (float*)(ws + LOG_OFF);
    unsigned short* gib    = (unsigned short*)(ws + GIB_OFF);
    unsigned short* ghb    = (unsigned short*)(ws + GHB_OFF);
    unsigned short* hnewb  = (unsigned short*)(ws + HNB_OFF);

    cvt_all_kernel<<<4305, 256, 0, stream>>>(hidden, w_ih, w_hh, comb_W, out_W,
                                             attn_W, last_input,
                                             cat1b, cat2b, wihb, whhb, combWb,
                                             outWb, awWb);
    scores_gemm_kernel<<<dim3(Bn / 64, 4), 256, 0, stream>>>(cat1b, awWb, attn_b, logits);
    softmax_kernel<<<Bn / 4, 256, 0, stream>>>(logits, out);
    attn_apply_kernel<<<Bn / 8, 256, 0, stream>>>(enc, out + AW_OFF, cat2b);
    comb_gemm_kernel<<<dim3(Bn / 128, Hn / 128), 256, 0, stream>>>(cat2b, combWb, comb_b, xb);
    gates_gemm_kernel<<<dim3(Bn / 128, 24), 256, 0, stream>>>(xb, cat1b, wihb, whhb,
                                                              b_ih, b_hh, gib, ghb);
    gru_elem_kernel<<<2048, 256, 0, stream>>>(gib, ghb, hidden, out, hnewb);
    out_gemm_kernel<<<Bn / 128, 256, 0, stream>>>(hnewb, outWb, out_b, out);
}